// Round 18
// baseline (1817.451 us; speedup 1.0000x reference)
//
#include <hip/hip_runtime.h>
#include <cstdio>
#include <cstdint>

constexpr int N_NODES = 20000;
constexpr int E_EDGES = 640000;
constexpr int S_STORIES = 32;
constexpr int G_TOT = 33;          // graph 0 = persona, 1..32 = stories
constexpr int IN_DIM = 384;
constexpr int HID = 128;
constexpr int F_OUT = 64;
constexpr float NEG_SLOPE = 0.2f;

// CSR build geometry
constexpr int EPB = 8192;
constexpr int NB = (E_EDGES + EPB - 1) / EPB;      // 79
constexpr int NBUCK = (N_NODES + 63) / 64;         // 313

constexpr int CNT_BLOCKS  = G_TOT * NB;            // 2607
constexpr int WPREP_ELEMS = 2 * HID * IN_DIM + 2 * F_OUT * HID;  // 114688
constexpr int WPREP_BLOCKS = (WPREP_ELEMS + 255) / 256;          // 448
constexpr int ZERO_BLOCKS = (G_TOT * 64 + 255) / 256;            // 9
constexpr int MM_BPG = (N_NODES + 127) / 128;      // 157
constexpr int MM_BLOCKS = G_TOT * MM_BPG;          // 5181
constexpr int MM_HALF_A = MM_BLOCKS / 2;           // 2590
constexpr int MM_HALF_B = MM_BLOCKS - MM_HALF_A;   // 2591
constexpr int FINE_BLOCKS = G_TOT * NBUCK;         // 10329

typedef _Float16 half8 __attribute__((ext_vector_type(8)));
typedef _Float16 h2 __attribute__((ext_vector_type(2)));
typedef float f32x4 __attribute__((ext_vector_type(4)));

__device__ __forceinline__ float leaky(float x) { return x > 0.f ? x : NEG_SLOPE * x; }

// fp16 pack/unpack
__device__ __forceinline__ uint32_t pkh2(float lo, float hi) {
    return __builtin_bit_cast(uint32_t, __builtin_amdgcn_cvt_pkrtz(lo, hi));
}
__device__ __forceinline__ float hlo(uint32_t u) {
    h2 h = __builtin_bit_cast(h2, u); return (float)h.x;
}
__device__ __forceinline__ float hhi(uint32_t u) {
    h2 h = __builtin_bit_cast(h2, u); return (float)h.y;
}
__device__ __forceinline__ uint16_t f2h(float x) {
    return __builtin_bit_cast(uint16_t, (_Float16)x);
}
__device__ __forceinline__ h2 h2shflx(h2 v, int mask) {
    return __builtin_bit_cast(h2, __shfl_xor(__builtin_bit_cast(int, v), mask));
}

// ================= device bodies (whole block enters one body) =================

__device__ __forceinline__ void count_body(int blk, unsigned* cnt,
                                           const int* __restrict__ pei, const int* __restrict__ sei,
                                           unsigned* __restrict__ C) {
    int g = blk / NB, k = blk - g * NB;
    const int* ei = (g == 0) ? pei : sei + (size_t)(g - 1) * 2 * E_EDGES;
    const int* dstp = ei + E_EDGES;
    int lo = k * EPB, hi = min(lo + EPB, E_EDGES);
    for (int i = threadIdx.x; i < NBUCK; i += 256) cnt[i] = 0;
    __syncthreads();
    for (int i = lo + threadIdx.x; i < hi; i += 256)
        atomicAdd(&cnt[dstp[i] >> 6], 1u);
    __syncthreads();
    unsigned* Cb = C + ((size_t)g * NB + k) * NBUCK;
    for (int i = threadIdx.x; i < NBUCK; i += 256) Cb[i] = cnt[i];
}

__device__ __forceinline__ void wprep_body(int blk,
                                           const float* __restrict__ pW1, const float* __restrict__ sW1,
                                           const float* __restrict__ pW2, const float* __restrict__ sW2,
                                           short* __restrict__ w1t, short* __restrict__ w2t) {
    constexpr int N1 = 2 * HID * IN_DIM;
    constexpr int N2 = 2 * F_OUT * HID;
    int idx = blk * 256 + threadIdx.x;
    if (idx < N1) {
        int t = idx / (HID * IN_DIM);
        int r = idx % (HID * IN_DIM);
        int col = r / IN_DIM, k = r % IN_DIM;
        const float* W = t ? sW1 : pW1;
        float v = W[(size_t)k * HID + col];
        _Float16 hi = (_Float16)v;
        w1t[idx]      = __builtin_bit_cast(short, hi);
        w1t[idx + N1] = __builtin_bit_cast(short, (_Float16)(v - (float)hi));
    } else if (idx < N1 + N2) {
        int j = idx - N1;
        int t = j / (F_OUT * HID);
        int r = j % (F_OUT * HID);
        int col = r / HID, k = r % HID;
        const float* W = t ? sW2 : pW2;
        float v = W[(size_t)k * F_OUT + col];
        _Float16 hi = (_Float16)v;
        w2t[j]      = __builtin_bit_cast(short, hi);
        w2t[j + N2] = __builtin_bit_cast(short, (_Float16)(v - (float)hi));
    }
}

__device__ __forceinline__ void bucket_body(int blk, unsigned* off,
                                            const int* __restrict__ pei, const int* __restrict__ sei,
                                            const unsigned* __restrict__ C, unsigned* __restrict__ tmp) {
    int g = blk / NB, k = blk - g * NB;
    const int* ei = (g == 0) ? pei : sei + (size_t)(g - 1) * 2 * E_EDGES;
    int lo = k * EPB, hi = min(lo + EPB, E_EDGES);
    const unsigned* Cb = C + ((size_t)g * NB + k) * NBUCK;
    for (int i = threadIdx.x; i < NBUCK; i += 256) off[i] = Cb[i];
    __syncthreads();
    unsigned* tg = tmp + (size_t)g * E_EDGES;
    for (int i = lo + threadIdx.x; i < hi; i += 256) {
        int s = ei[i], d = ei[E_EDGES + i];
        unsigned r = atomicAdd(&off[d >> 6], 1u);
        tg[r] = ((unsigned)(d & 63) << 15) | (unsigned)s;
    }
}

__device__ __forceinline__ void fine_body(int blk, unsigned* cnt, unsigned* pos,
                                          const unsigned* __restrict__ tmp, const unsigned* __restrict__ BB,
                                          int* __restrict__ row, int* __restrict__ csr_src) {
    int g = blk / NBUCK, b = blk - g * NBUCK;
    unsigned lo = BB[(size_t)g * (NBUCK + 1) + b];
    unsigned hi = BB[(size_t)g * (NBUCK + 1) + b + 1];
    if (threadIdx.x < 64) cnt[threadIdx.x] = 0;
    __syncthreads();
    const unsigned* tg = tmp + (size_t)g * E_EDGES;
    for (unsigned i = lo + threadIdx.x; i < hi; i += 256)
        atomicAdd(&cnt[(tg[i] >> 15) & 63], 1u);
    __syncthreads();
    if (threadIdx.x < 64) {
        unsigned v = cnt[threadIdx.x];
        unsigned inc = v;
#pragma unroll
        for (int o = 1; o < 64; o <<= 1) {
            unsigned u = __shfl_up(inc, o);
            if ((int)threadIdx.x >= o) inc += u;
        }
        unsigned e = inc - v;
        pos[threadIdx.x] = lo + e;
        int n = b * 64 + (int)threadIdx.x;
        if (n <= N_NODES) row[(size_t)g * (N_NODES + 1) + n] = (int)(lo + e);
    }
    __syncthreads();
    for (unsigned i = lo + threadIdx.x; i < hi; i += 256) {
        unsigned v = tg[i];
        unsigned r = atomicAdd(&pos[(v >> 15) & 63], 1u);
        csr_src[(size_t)g * E_EDGES + r] = (int)(v & 0x7fffu);
    }
}

// ---------- MFMA GEMM body (fp16) + fused as/ad epilogue ----------
template<int KDIM, int NCOL, bool CVT>
__device__ __forceinline__ void mm_body(int bid, char* smemc,
                                        const void* __restrict__ pXv, const void* __restrict__ sXv,
                                        const short* __restrict__ wt,
                                        const float* __restrict__ pa, const float* __restrict__ sa,
                                        uint16_t* __restrict__ outb,
                                        float* __restrict__ as_, float* __restrict__ ad_) {
    constexpr int NT = NCOL / 16;
    int g = bid / MM_BPG;
    int brow = (bid % MM_BPG) * 128;
    const short* wtg = wt + (g ? (size_t)NCOL * KDIM : 0);
    short* As = (short*)smemc;          // 128*40
    short* Bh = As + 128 * 40;          // NCOL*40
    short* Bl = Bh + NCOL * 40;         // NCOL*40
    int tid = threadIdx.x;
    int w = tid >> 6, l = tid & 63;
    int lr = l & 15, kq = l >> 4;
    f32x4 acc[2][NT] = {};
    for (int k0 = 0; k0 < KDIM; k0 += 32) {
        if (CVT) {
            const float* X = (g == 0) ? (const float*)pXv
                                      : (const float*)sXv + (size_t)(g - 1) * N_NODES * KDIM;
#pragma unroll
            for (int i = 0; i < 4; ++i) {                 // 128 rows x 8 float4 = 1024 transactions
                int v = tid + i * 256;
                int r = v >> 3, q = v & 7;
                float4 xv = make_float4(0.f, 0.f, 0.f, 0.f);
                if (brow + r < N_NODES)
                    xv = *(const float4*)(X + (size_t)(brow + r) * KDIM + k0 + q * 4);
                uint2 pkd; pkd.x = pkh2(xv.x, xv.y); pkd.y = pkh2(xv.z, xv.w);
                *(uint2*)(As + r * 40 + q * 4) = pkd;
            }
        } else {
            const uint16_t* X = (g == 0) ? (const uint16_t*)pXv
                                         : (const uint16_t*)sXv + (size_t)(g - 1) * N_NODES * KDIM;
#pragma unroll
            for (int i = 0; i < 2; ++i) {                 // 128 rows x 4 uint4 = 512 transactions
                int v = tid + i * 256;
                int r = v >> 2, q = v & 3;
                uint4 xv = make_uint4(0u, 0u, 0u, 0u);
                if (brow + r < N_NODES)
                    xv = *(const uint4*)(X + (size_t)(brow + r) * KDIM + k0 + q * 8);
                *(uint4*)(As + r * 40 + q * 8) = xv;
            }
        }
        for (int v = tid; v < NCOL * 4; v += 256) {       // B: NCOL rows x 4 uint4, hi+lo
            int r = v >> 2, q = v & 3;
            const short* srcp = wtg + (size_t)r * KDIM + k0 + q * 8;
            *(uint4*)(Bh + r * 40 + q * 8) = *(const uint4*)srcp;
            *(uint4*)(Bl + r * 40 + q * 8) = *(const uint4*)(srcp + (size_t)2 * NCOL * KDIM);
        }
        __syncthreads();
        half8 a0 = *(const half8*)(As + (w * 32 + lr) * 40 + kq * 8);
        half8 a1 = *(const half8*)(As + (w * 32 + 16 + lr) * 40 + kq * 8);
#pragma unroll
        for (int ct = 0; ct < NT; ++ct) {
            half8 bh = *(const half8*)(Bh + (ct * 16 + lr) * 40 + kq * 8);
            half8 bl = *(const half8*)(Bl + (ct * 16 + lr) * 40 + kq * 8);
            acc[0][ct] = __builtin_amdgcn_mfma_f32_16x16x32_f16(a0, bh, acc[0][ct], 0, 0, 0);
            acc[0][ct] = __builtin_amdgcn_mfma_f32_16x16x32_f16(a0, bl, acc[0][ct], 0, 0, 0);
            acc[1][ct] = __builtin_amdgcn_mfma_f32_16x16x32_f16(a1, bh, acc[1][ct], 0, 0, 0);
            acc[1][ct] = __builtin_amdgcn_mfma_f32_16x16x32_f16(a1, bl, acc[1][ct], 0, 0, 0);
        }
        __syncthreads();
    }
    // epilogue: store f16 h; fused as/ad from fp32 acc
    const float* av = (g == 0) ? pa : sa;   // 2*NCOL floats: [a_src | a_dst]
    float aS[NT], aD[NT];
#pragma unroll
    for (int ct = 0; ct < NT; ++ct) {
        aS[ct] = av[ct * 16 + lr];
        aD[ct] = av[NCOL + ct * 16 + lr];
    }
#pragma unroll
    for (int rt = 0; rt < 2; ++rt) {
#pragma unroll
        for (int i = 0; i < 4; ++i) {
            int node = brow + w * 32 + rt * 16 + kq * 4 + i;
            float s = 0.f, d = 0.f;
#pragma unroll
            for (int ct = 0; ct < NT; ++ct) {
                float h = acc[rt][ct][i];
                s += h * aS[ct];
                d += h * aD[ct];
                if (node < N_NODES)
                    outb[((size_t)g * N_NODES + node) * NCOL + ct * 16 + lr] = f2h(h);
            }
#pragma unroll
            for (int off = 1; off < 16; off <<= 1) { s += __shfl_xor(s, off); d += __shfl_xor(d, off); }
            if (lr == 0 && node < N_NODES) {
                as_[(size_t)g * N_NODES + node] = s;
                ad_[(size_t)g * N_NODES + node] = d;
            }
        }
    }
}

// ================= kernels =================

// K0: csr_count ∥ wprep ∥ zero emb
__global__ __launch_bounds__(256) void k0_kernel(const int* __restrict__ pei, const int* __restrict__ sei,
                                                 unsigned* __restrict__ C,
                                                 const float* __restrict__ pW1, const float* __restrict__ sW1,
                                                 const float* __restrict__ pW2, const float* __restrict__ sW2,
                                                 short* __restrict__ w1t, short* __restrict__ w2t,
                                                 float* __restrict__ emb) {
    __shared__ unsigned cnt[NBUCK];
    int bid = blockIdx.x;
    if (bid < CNT_BLOCKS) {
        count_body(bid, cnt, pei, sei, C);
    } else if (bid < CNT_BLOCKS + WPREP_BLOCKS) {
        wprep_body(bid - CNT_BLOCKS, pW1, sW1, pW2, sW2, w1t, w2t);
    } else {
        int idx = (bid - CNT_BLOCKS - WPREP_BLOCKS) * 256 + threadIdx.x;
        if (idx < G_TOT * 64) emb[idx] = 0.f;
    }
}

// CSR phase B (unchanged, 512 threads)
__global__ __launch_bounds__(512) void csr_scan(unsigned* __restrict__ C, unsigned* __restrict__ BB) {
    int g = blockIdx.x;
    __shared__ unsigned tot[NBUCK + 1];
    unsigned* Cg = C + (size_t)g * NB * NBUCK;
    for (int b = threadIdx.x; b < NBUCK; b += 512) {
        unsigned s = 0;
        for (int k = 0; k < NB; ++k) s += Cg[(size_t)k * NBUCK + b];
        tot[b] = s;
    }
    __syncthreads();
    if (threadIdx.x == 0) {
        unsigned run = 0;
        for (int b = 0; b < NBUCK; ++b) { unsigned t = tot[b]; tot[b] = run; run += t; }
        tot[NBUCK] = run;
    }
    __syncthreads();
    for (int b = threadIdx.x; b <= NBUCK; b += 512) BB[(size_t)g * (NBUCK + 1) + b] = tot[b];
    for (int b = threadIdx.x; b < NBUCK; b += 512) {
        unsigned run = tot[b];
        for (int k = 0; k < NB; ++k) {
            unsigned t = Cg[(size_t)k * NBUCK + b];
            Cg[(size_t)k * NBUCK + b] = run;
            run += t;
        }
    }
}

// K2: mm1 first half ∥ csr_bucket
__global__ __launch_bounds__(256) void mm_bucket_kernel(const void* __restrict__ pXv, const void* __restrict__ sXv,
                                                        const short* __restrict__ wt,
                                                        const float* __restrict__ pa, const float* __restrict__ sa,
                                                        uint16_t* __restrict__ outb,
                                                        float* __restrict__ as_, float* __restrict__ ad_,
                                                        const int* __restrict__ pei, const int* __restrict__ sei,
                                                        const unsigned* __restrict__ C, unsigned* __restrict__ tmp) {
    constexpr int SM = (128 * 40 + HID * 40 * 2) * 2;   // 30720 B
    __shared__ __align__(16) char smem[SM];
    int bid = blockIdx.x;
    if (bid < MM_HALF_A)
        mm_body<IN_DIM, HID, true>(bid, smem, pXv, sXv, wt, pa, sa, outb, as_, ad_);
    else
        bucket_body(bid - MM_HALF_A, (unsigned*)smem, pei, sei, C, tmp);
}

// K3: mm1 second half ∥ csr_fine
__global__ __launch_bounds__(256) void mm_fine_kernel(const void* __restrict__ pXv, const void* __restrict__ sXv,
                                                      const short* __restrict__ wt,
                                                      const float* __restrict__ pa, const float* __restrict__ sa,
                                                      uint16_t* __restrict__ outb,
                                                      float* __restrict__ as_, float* __restrict__ ad_,
                                                      const unsigned* __restrict__ tmp, const unsigned* __restrict__ BB,
                                                      int* __restrict__ row, int* __restrict__ csr_src) {
    constexpr int SM = (128 * 40 + HID * 40 * 2) * 2;
    __shared__ __align__(16) char smem[SM];
    int bid = blockIdx.x;
    if (bid < MM_HALF_B)
        mm_body<IN_DIM, HID, true>(bid + MM_HALF_A, smem, pXv, sXv, wt, pa, sa, outb, as_, ad_);
    else {
        unsigned* cnt = (unsigned*)smem;
        fine_body(bid - MM_HALF_B, cnt, cnt + 64, tmp, BB, row, csr_src);
    }
}

// mm2 standalone
__global__ __launch_bounds__(256) void mm_only_kernel(const void* __restrict__ pXv, const void* __restrict__ sXv,
                                                      const short* __restrict__ wt,
                                                      const float* __restrict__ pa, const float* __restrict__ sa,
                                                      uint16_t* __restrict__ outb,
                                                      float* __restrict__ as_, float* __restrict__ ad_) {
    constexpr int SM = (128 * 40 + F_OUT * 40 * 2) * 2;  // 20480 B
    __shared__ __align__(16) char smem[SM];
    mm_body<HID, F_OUT, false>(blockIdx.x, smem, pXv, sXv, wt, pa, sa, outb, as_, ad_);
}

// ---------- GAT aggregation, F=128: online softmax; gathers prefetched ahead of score math ----------
__global__ __launch_bounds__(256) void agg128_kernel(const uint32_t* __restrict__ hb,
                                                     const float* __restrict__ as_, const float* __restrict__ ad_,
                                                     const int* __restrict__ row, const int* __restrict__ csr_src,
                                                     const float* __restrict__ pb, const float* __restrict__ sb,
                                                     uint32_t* __restrict__ h1p) {
    int node = blockIdx.x * 4 + (threadIdx.x >> 6);
    int g = node / N_NODES;
    int n = node - g * N_NODES;
    int lane = threadIdx.x & 63;
    int start = row[(size_t)g * (N_NODES + 1) + n];
    int end   = row[(size_t)g * (N_NODES + 1) + n + 1];
    const int* src = csr_src + (size_t)g * E_EDGES;
    const float* asg = as_ + (size_t)g * N_NODES;
    const uint32_t* hg = hb + (size_t)g * N_NODES * 64;
    const char* hgb = (const char*)hg;   // block-uniform base; 32-bit voffsets
    float ad_d = ad_[node];
    float e_self = leaky(asg[n] + ad_d);
    int grp = lane >> 4;                 // edge slot within quad
    int f = lane & 15;                   // uint4 slice: feats f*8 .. f*8+7
    int fb = f << 4;                     // byte offset within 256 B row
    float m = e_self, denomp = 0.f;
    h2 A0 = {}, A1 = {}, A2 = {}, A3 = {};   // 8 feats as 4 packed pairs
    for (int j0 = start; j0 < end; j0 += 64) {
        int j = j0 + lane;
        float e = -3.0e38f; int ofs0 = 0;
        if (j < end) { int s0 = src[j]; ofs0 = s0 << 8; e = leaky(asg[s0] + ad_d); }
        int cnt = min(64, end - j0);
        // prefetch first superstep's gathers NOW — addresses don't depend on softmax;
        // their ~300-cycle latency hides under the cmax reduce + exp below.
        uint4 hvA, hvB;
        {
            int oA = __shfl(ofs0, grp);
            int oB = __shfl(ofs0, 4 + grp);
            hvA = *(const uint4*)(hgb + (unsigned)(oA + fb));
            hvB = *(const uint4*)(hgb + (unsigned)(oB + fb));
        }
        float cmax = e;
#pragma unroll
        for (int off = 32; off; off >>= 1) cmax = fmaxf(cmax, __shfl_xor(cmax, off));
        if (cmax > m) {                  // wave-uniform rescale (rare)
            float sc = __expf(m - cmax);
            denomp *= sc;
            _Float16 sh = (_Float16)sc;
            h2 s2 = {sh, sh};
            A0 *= s2; A1 *= s2; A2 *= s2; A3 *= s2;
            m = cmax;
        }
        float w0 = (j < end) ? __expf(e - m) : 0.f;
        denomp += w0;
        for (int t = 0; t < cnt; t += 8) {
            float wA = __shfl(w0, t + grp);
            float wB = __shfl(w0, t + 4 + grp);
            uint4 cA = hvA, cB = hvB;
            if (t + 8 < cnt) {           // wave-uniform; prefetch next superstep
                int oA = __shfl(ofs0, t + 8 + grp);
                int oB = __shfl(ofs0, t + 12 + grp);
                hvA = *(const uint4*)(hgb + (unsigned)(oA + fb));
                hvB = *(const uint4*)(hgb + (unsigned)(oB + fb));
            }
            _Float16 whA = (_Float16)wA, whB = (_Float16)wB;
            h2 w2A = {whA, whA}, w2B = {whB, whB};
            A0 += w2A * __builtin_bit_cast(h2, cA.x);
            A1 += w2A * __builtin_bit_cast(h2, cA.y);
            A2 += w2A * __builtin_bit_cast(h2, cA.z);
            A3 += w2A * __builtin_bit_cast(h2, cA.w);
            A0 += w2B * __builtin_bit_cast(h2, cB.x);
            A1 += w2B * __builtin_bit_cast(h2, cB.y);
            A2 += w2B * __builtin_bit_cast(h2, cB.z);
            A3 += w2B * __builtin_bit_cast(h2, cB.w);
        }
    }
#pragma unroll
    for (int off = 32; off; off >>= 1) denomp += __shfl_xor(denomp, off);
#pragma unroll
    for (int off = 16; off <= 32; off <<= 1) {
        A0 += h2shflx(A0, off); A1 += h2shflx(A1, off);
        A2 += h2shflx(A2, off); A3 += h2shflx(A3, off);
    }
    if (lane < 16) {
        float wself = __expf(e_self - m);
        float inv = 1.f / (denomp + wself + 1e-16f);
        uint4 hv = *(const uint4*)(hg + (size_t)n * 64 + lane * 4);
        const float* b = (g == 0) ? pb : sb;
        float4 b0 = *(const float4*)(b + lane * 8);
        float4 b1 = *(const float4*)(b + lane * 8 + 4);
        float o0 = fmaxf(fmaf(wself, hlo(hv.x), (float)A0.x) * inv + b0.x, 0.f);
        float o1 = fmaxf(fmaf(wself, hhi(hv.x), (float)A0.y) * inv + b0.y, 0.f);
        float o2 = fmaxf(fmaf(wself, hlo(hv.y), (float)A1.x) * inv + b0.z, 0.f);
        float o3 = fmaxf(fmaf(wself, hhi(hv.y), (float)A1.y) * inv + b0.w, 0.f);
        float o4 = fmaxf(fmaf(wself, hlo(hv.z), (float)A2.x) * inv + b1.x, 0.f);
        float o5 = fmaxf(fmaf(wself, hhi(hv.z), (float)A2.y) * inv + b1.y, 0.f);
        float o6 = fmaxf(fmaf(wself, hlo(hv.w), (float)A3.x) * inv + b1.z, 0.f);
        float o7 = fmaxf(fmaf(wself, hhi(hv.w), (float)A3.y) * inv + b1.w, 0.f);
        uint4 o; o.x = pkh2(o0, o1); o.y = pkh2(o2, o3); o.z = pkh2(o4, o5); o.w = pkh2(o6, o7);
        *(uint4*)(h1p + (size_t)node * 64 + lane * 4) = o;
    }
}

// ---------- GAT aggregation, F=64: online softmax + 4-deep pipelined f16 gather; pk_fma acc; f16 out ----------
__global__ __launch_bounds__(256) void agg64_kernel(const uint32_t* __restrict__ hb,
                                                    const float* __restrict__ as_, const float* __restrict__ ad_,
                                                    const int* __restrict__ row, const int* __restrict__ csr_src,
                                                    const float* __restrict__ pb, const float* __restrict__ sb,
                                                    uint32_t* __restrict__ out2b) {
    int node = blockIdx.x * 4 + (threadIdx.x >> 6);
    int g = node / N_NODES;
    int n = node - g * N_NODES;
    int lane = threadIdx.x & 63;
    int start = row[(size_t)g * (N_NODES + 1) + n];
    int end   = row[(size_t)g * (N_NODES + 1) + n + 1];
    const int* src = csr_src + (size_t)g * E_EDGES;
    const float* asg = as_ + (size_t)g * N_NODES;
    const uint32_t* hg = hb + (size_t)g * N_NODES * 32;
    const char* hgb = (const char*)hg;   // 128 B rows
    float ad_d = ad_[node];
    float e_self = leaky(asg[n] + ad_d);
    int grp = lane >> 4;
    int f = lane & 15;                   // uint2 slice: feats f*4 .. f*4+3
    int fb = f << 3;
    float m = e_self, denomp = 0.f;
    h2 A0 = {}, A1 = {};
    for (int j0 = start; j0 < end; j0 += 64) {
        int j = j0 + lane;
        float e = -3.0e38f; int ofs0 = 0;
        if (j < end) { int s0 = src[j]; ofs0 = s0 << 7; e = leaky(asg[s0] + ad_d); }
        float cmax = e;
#pragma unroll
        for (int off = 32; off; off >>= 1) cmax = fmaxf(cmax, __shfl_xor(cmax, off));
        if (cmax > m) {
            float sc = __expf(m - cmax);
            denomp *= sc;
            _Float16 sh = (_Float16)sc;
            h2 s2 = {sh, sh};
            A0 *= s2; A1 *= s2;
            m = cmax;
        }
        float w0 = (j < end) ? __expf(e - m) : 0.f;
        denomp += w0;
        int cnt = min(64, end - j0);
        for (int t = 0; t < cnt; t += 16) {
            float w_[4]; int o_[4];
#pragma unroll
            for (int u = 0; u < 4; ++u) {
                int tt = t + u * 4 + grp;
                w_[u] = __shfl(w0, tt);
                o_[u] = __shfl(ofs0, tt);
            }
            uint2 hv_[4];
#pragma unroll
            for (int u = 0; u < 4; ++u)
                hv_[u] = *(const uint2*)(hgb + (unsigned)(o_[u] + fb));
#pragma unroll
            for (int u = 0; u < 4; ++u) {
                _Float16 wh = (_Float16)w_[u];
                h2 w2 = {wh, wh};
                uint2 hv = hv_[u];
                A0 += w2 * __builtin_bit_cast(h2, hv.x);
                A1 += w2 * __builtin_bit_cast(h2, hv.y);
            }
        }
    }
#pragma unroll
    for (int off = 32; off; off >>= 1) denomp += __shfl_xor(denomp, off);
#pragma unroll
    for (int off = 16; off <= 32; off <<= 1) {
        A0 += h2shflx(A0, off); A1 += h2shflx(A1, off);
    }
    if (lane < 16) {
        float wself = __expf(e_self - m);
        float inv = 1.f / (denomp + wself + 1e-16f);
        uint2 hv = *(const uint2*)(hg + (size_t)n * 32 + lane * 2);
        const float* b = (g == 0) ? pb : sb;
        float4 bv = *(const float4*)(b + lane * 4);
        float o0 = fmaf(wself, hlo(hv.x), (float)A0.x) * inv + bv.x;
        float o1 = fmaf(wself, hhi(hv.x), (float)A0.y) * inv + bv.y;
        float o2 = fmaf(wself, hlo(hv.y), (float)A1.x) * inv + bv.z;
        float o3 = fmaf(wself, hhi(hv.y), (float)A1.y) * inv + bv.w;
        uint2 o; o.x = pkh2(o0, o1); o.y = pkh2(o2, o3);
        *(uint2*)(out2b + (size_t)node * 32 + lane * 2) = o;
    }
}

// ---------- mean over nodes (f16 in) -> emb[g][64] ----------
__global__ __launch_bounds__(256) void mean_kernel(const uint32_t* __restrict__ out2b, float* __restrict__ emb) {
    constexpr int CH = 32;
    int g = blockIdx.x / CH, chunk = blockIdx.x % CH;
    int sub = threadIdx.x >> 5;          // 8 node groups
    int q = threadIdx.x & 31;            // u32 idx: feats 2q, 2q+1
    const uint32_t* og = out2b + (size_t)g * N_NODES * 32;
    float a0 = 0.f, a1 = 0.f;
    for (int n = chunk * 8 + sub; n < N_NODES; n += CH * 8) {
        uint32_t v = og[(size_t)n * 32 + q];
        a0 += hlo(v); a1 += hhi(v);
    }
    __shared__ float red[256][2];
    red[threadIdx.x][0] = a0; red[threadIdx.x][1] = a1;
    __syncthreads();
    if (sub == 0) {
        float s0 = 0.f, s1 = 0.f;
        for (int k = 0; k < 8; ++k) { s0 += red[k * 32 + q][0]; s1 += red[k * 32 + q][1]; }
        atomicAdd(&emb[g * 64 + 2 * q],     s0 * (1.f / N_NODES));
        atomicAdd(&emb[g * 64 + 2 * q + 1], s1 * (1.f / N_NODES));
    }
}

// ---------- cosine-similarity head ----------
__global__ __launch_bounds__(64) void final_kernel(const float* __restrict__ emb,
                                                   const float* __restrict__ temp, float* __restrict__ out) {
    int lane = threadIdx.x;
    float pe = emb[lane];
    float pp = pe * pe;
#pragma unroll
    for (int off = 32; off; off >>= 1) pp += __shfl_xor(pp, off);
    float t = temp[0];
    float pn = sqrtf(pp);
    for (int s_i = 0; s_i < S_STORIES; ++s_i) {
        float se = emb[(1 + s_i) * 64 + lane];
        float ss = se * se;
        float dt = se * pe;
#pragma unroll
        for (int off = 32; off; off >>= 1) { ss += __shfl_xor(ss, off); dt += __shfl_xor(dt, off); }
        if (lane == 0) out[s_i] = dt / (sqrtf(ss) * pn * t);
    }
}

extern "C" void kernel_launch(void* const* d_in, const int* in_sizes, int n_in,
                              void* d_out, int out_size, void* d_ws, size_t ws_size,
                              hipStream_t stream) {
    const float* persona_x = (const float*)d_in[0];
    const int*   pei       = (const int*)d_in[1];
    const float* story_x   = (const float*)d_in[2];
    const int*   sei       = (const int*)d_in[3];
    const float* p_W1 = (const float*)d_in[4];
    const float* p_a1 = (const float*)d_in[5];
    const float* p_b1 = (const float*)d_in[6];
    const float* p_W2 = (const float*)d_in[7];
    const float* p_a2 = (const float*)d_in[8];
    const float* p_b2 = (const float*)d_in[9];
    const float* s_W1 = (const float*)d_in[10];
    const float* s_a1 = (const float*)d_in[11];
    const float* s_b1 = (const float*)d_in[12];
    const float* s_W2 = (const float*)d_in[13];
    const float* s_a2 = (const float*)d_in[14];
    const float* s_b2 = (const float*)d_in[15];
    const float* temp = (const float*)d_in[16];
    float* out = (float*)d_out;

    char* ws = (char*)d_ws;
    size_t off = 0;
    auto alloc = [&](size_t bytes) { char* p = ws + off; off += (bytes + 255) & ~(size_t)255; return p; };
    uint32_t* hb1  = (uint32_t*)alloc((size_t)G_TOT * N_NODES * 64 * 4);   // f16 h1; out2b alias
    uint32_t* h1p  = (uint32_t*)alloc((size_t)G_TOT * N_NODES * 64 * 4);   // f16 h1'; CSR C/BB alias
    uint32_t* hb2  = (uint32_t*)alloc((size_t)G_TOT * N_NODES * 32 * 4);   // f16 h2; CSR tmp alias (84.48 MB both)
    float* as_     = (float*)alloc((size_t)G_TOT * N_NODES * 4);
    float* ad_     = (float*)alloc((size_t)G_TOT * N_NODES * 4);
    int*   csr_row = (int*)  alloc((size_t)G_TOT * (N_NODES + 1) * 4);
    int*   csr_src = (int*)  alloc((size_t)G_TOT * E_EDGES * 4);
    float* emb     = (float*)alloc((size_t)G_TOT * 64 * 4);
    short* w1t     = (short*)alloc((size_t)2 * 2 * HID * IN_DIM * 2);      // [plane][type][col][K]
    short* w2t     = (short*)alloc((size_t)2 * 2 * F_OUT * HID * 2);
    if (off > ws_size) {
        fprintf(stderr, "kernel_launch: ws too small: need %zu have %zu\n", off, ws_size);
        return;
    }
    // CSR scratch aliases: tmp -> hb2 (dead until mm2); C/BB -> h1p (dead until agg128).
    unsigned* tmp = (unsigned*)hb2;
    unsigned* C   = (unsigned*)h1p;
    unsigned* BB  = (unsigned*)h1p + (size_t)G_TOT * NB * NBUCK;
    uint32_t* out2b = hb1;                                             // hb1 dead after agg128

    const int NODE_BLOCKS = G_TOT * N_NODES / 4; // 165000, exact

    // K0: csr_count ∥ wprep ∥ zero(emb)
    k0_kernel<<<CNT_BLOCKS + WPREP_BLOCKS + ZERO_BLOCKS, 256, 0, stream>>>(
        pei, sei, C, p_W1, s_W1, p_W2, s_W2, w1t, w2t, emb);
    // K1: per-graph scan
    csr_scan<<<G_TOT, 512, 0, stream>>>(C, BB);
    // K2: mm1 (first half) ∥ csr_bucket
    mm_bucket_kernel<<<MM_HALF_A + CNT_BLOCKS, 256, 0, stream>>>(
        persona_x, story_x, w1t, p_a1, s_a1, (uint16_t*)hb1, as_, ad_, pei, sei, C, tmp);
    // K3: mm1 (second half) ∥ csr_fine
    mm_fine_kernel<<<MM_HALF_B + FINE_BLOCKS, 256, 0, stream>>>(
        persona_x, story_x, w1t, p_a1, s_a1, (uint16_t*)hb1, as_, ad_, tmp, BB, csr_row, csr_src);

    // Layer 1 aggregation
    agg128_kernel<<<NODE_BLOCKS, 256, 0, stream>>>(hb1, as_, ad_, csr_row, csr_src, p_b1, s_b1, h1p);

    // Layer 2 (A operand already f16; as/ad fused) — hb2 (tmp) now dead, safe to overwrite
    const uint16_t* h1p16 = (const uint16_t*)h1p;
    mm_only_kernel<<<MM_BLOCKS, 256, 0, stream>>>(h1p16, h1p16 + (size_t)N_NODES * HID, w2t, p_a2, s_a2,
                                                  (uint16_t*)hb2, as_, ad_);
    agg64_kernel<<<NODE_BLOCKS, 256, 0, stream>>>(hb2, as_, ad_, csr_row, csr_src, p_b2, s_b2, out2b);

    // Readout
    mean_kernel<<<G_TOT * 32, 256, 0, stream>>>(out2b, emb);
    final_kernel<<<1, 64, 0, stream>>>(emb, temp, out);
}

// Round 19
// 1790.763 us; speedup vs baseline: 1.0149x; 1.0149x over previous
//
#include <hip/hip_runtime.h>
#include <cstdio>
#include <cstdint>

constexpr int N_NODES = 20000;
constexpr int E_EDGES = 640000;
constexpr int S_STORIES = 32;
constexpr int G_TOT = 33;          // graph 0 = persona, 1..32 = stories
constexpr int IN_DIM = 384;
constexpr int HID = 128;
constexpr int F_OUT = 64;
constexpr float NEG_SLOPE = 0.2f;

// CSR build geometry
constexpr int EPB = 8192;
constexpr int NB = (E_EDGES + EPB - 1) / EPB;      // 79
constexpr int NBUCK = (N_NODES + 63) / 64;         // 313

constexpr int CNT_BLOCKS  = G_TOT * NB;            // 2607
constexpr int WPREP_ELEMS = 2 * HID * IN_DIM + 2 * F_OUT * HID;  // 114688
constexpr int WPREP_BLOCKS = (WPREP_ELEMS + 255) / 256;          // 448
constexpr int ZERO_BLOCKS = (G_TOT * 64 + 255) / 256;            // 9
constexpr int MM_BPG = (N_NODES + 127) / 128;      // 157
constexpr int MM_BLOCKS = G_TOT * MM_BPG;          // 5181
constexpr int MM_HALF_A = MM_BLOCKS / 2;           // 2590
constexpr int MM_HALF_B = MM_BLOCKS - MM_HALF_A;   // 2591
constexpr int FINE_BLOCKS = G_TOT * NBUCK;         // 10329

typedef _Float16 half8 __attribute__((ext_vector_type(8)));
typedef _Float16 h2 __attribute__((ext_vector_type(2)));
typedef float f32x4 __attribute__((ext_vector_type(4)));

__device__ __forceinline__ float leaky(float x) { return x > 0.f ? x : NEG_SLOPE * x; }

// fp16 pack/unpack
__device__ __forceinline__ uint32_t pkh2(float lo, float hi) {
    return __builtin_bit_cast(uint32_t, __builtin_amdgcn_cvt_pkrtz(lo, hi));
}
__device__ __forceinline__ float hlo(uint32_t u) {
    h2 h = __builtin_bit_cast(h2, u); return (float)h.x;
}
__device__ __forceinline__ float hhi(uint32_t u) {
    h2 h = __builtin_bit_cast(h2, u); return (float)h.y;
}
__device__ __forceinline__ uint16_t f2h(float x) {
    return __builtin_bit_cast(uint16_t, (_Float16)x);
}
__device__ __forceinline__ h2 h2shflx(h2 v, int mask) {
    return __builtin_bit_cast(h2, __shfl_xor(__builtin_bit_cast(int, v), mask));
}

// ================= device bodies (whole block enters one body) =================

__device__ __forceinline__ void count_body(int blk, unsigned* cnt,
                                           const int* __restrict__ pei, const int* __restrict__ sei,
                                           unsigned* __restrict__ C) {
    int g = blk / NB, k = blk - g * NB;
    const int* ei = (g == 0) ? pei : sei + (size_t)(g - 1) * 2 * E_EDGES;
    const int* dstp = ei + E_EDGES;
    int lo = k * EPB, hi = min(lo + EPB, E_EDGES);
    for (int i = threadIdx.x; i < NBUCK; i += 256) cnt[i] = 0;
    __syncthreads();
    for (int i = lo + threadIdx.x; i < hi; i += 256)
        atomicAdd(&cnt[dstp[i] >> 6], 1u);
    __syncthreads();
    unsigned* Cb = C + ((size_t)g * NB + k) * NBUCK;
    for (int i = threadIdx.x; i < NBUCK; i += 256) Cb[i] = cnt[i];
}

__device__ __forceinline__ void wprep_body(int blk,
                                           const float* __restrict__ pW1, const float* __restrict__ sW1,
                                           const float* __restrict__ pW2, const float* __restrict__ sW2,
                                           short* __restrict__ w1t, short* __restrict__ w2t) {
    constexpr int N1 = 2 * HID * IN_DIM;
    constexpr int N2 = 2 * F_OUT * HID;
    int idx = blk * 256 + threadIdx.x;
    if (idx < N1) {
        int t = idx / (HID * IN_DIM);
        int r = idx % (HID * IN_DIM);
        int col = r / IN_DIM, k = r % IN_DIM;
        const float* W = t ? sW1 : pW1;
        float v = W[(size_t)k * HID + col];
        _Float16 hi = (_Float16)v;
        w1t[idx]      = __builtin_bit_cast(short, hi);
        w1t[idx + N1] = __builtin_bit_cast(short, (_Float16)(v - (float)hi));
    } else if (idx < N1 + N2) {
        int j = idx - N1;
        int t = j / (F_OUT * HID);
        int r = j % (F_OUT * HID);
        int col = r / HID, k = r % HID;
        const float* W = t ? sW2 : pW2;
        float v = W[(size_t)k * F_OUT + col];
        _Float16 hi = (_Float16)v;
        w2t[j]      = __builtin_bit_cast(short, hi);
        w2t[j + N2] = __builtin_bit_cast(short, (_Float16)(v - (float)hi));
    }
}

__device__ __forceinline__ void bucket_body(int blk, unsigned* off,
                                            const int* __restrict__ pei, const int* __restrict__ sei,
                                            const unsigned* __restrict__ C, unsigned* __restrict__ tmp) {
    int g = blk / NB, k = blk - g * NB;
    const int* ei = (g == 0) ? pei : sei + (size_t)(g - 1) * 2 * E_EDGES;
    int lo = k * EPB, hi = min(lo + EPB, E_EDGES);
    const unsigned* Cb = C + ((size_t)g * NB + k) * NBUCK;
    for (int i = threadIdx.x; i < NBUCK; i += 256) off[i] = Cb[i];
    __syncthreads();
    unsigned* tg = tmp + (size_t)g * E_EDGES;
    for (int i = lo + threadIdx.x; i < hi; i += 256) {
        int s = ei[i], d = ei[E_EDGES + i];
        unsigned r = atomicAdd(&off[d >> 6], 1u);
        tg[r] = ((unsigned)(d & 63) << 15) | (unsigned)s;
    }
}

__device__ __forceinline__ void fine_body(int blk, unsigned* cnt, unsigned* pos,
                                          const unsigned* __restrict__ tmp, const unsigned* __restrict__ BB,
                                          int* __restrict__ row, int* __restrict__ csr_src) {
    int g = blk / NBUCK, b = blk - g * NBUCK;
    unsigned lo = BB[(size_t)g * (NBUCK + 1) + b];
    unsigned hi = BB[(size_t)g * (NBUCK + 1) + b + 1];
    if (threadIdx.x < 64) cnt[threadIdx.x] = 0;
    __syncthreads();
    const unsigned* tg = tmp + (size_t)g * E_EDGES;
    for (unsigned i = lo + threadIdx.x; i < hi; i += 256)
        atomicAdd(&cnt[(tg[i] >> 15) & 63], 1u);
    __syncthreads();
    if (threadIdx.x < 64) {
        unsigned v = cnt[threadIdx.x];
        unsigned inc = v;
#pragma unroll
        for (int o = 1; o < 64; o <<= 1) {
            unsigned u = __shfl_up(inc, o);
            if ((int)threadIdx.x >= o) inc += u;
        }
        unsigned e = inc - v;
        pos[threadIdx.x] = lo + e;
        int n = b * 64 + (int)threadIdx.x;
        if (n <= N_NODES) row[(size_t)g * (N_NODES + 1) + n] = (int)(lo + e);
    }
    __syncthreads();
    for (unsigned i = lo + threadIdx.x; i < hi; i += 256) {
        unsigned v = tg[i];
        unsigned r = atomicAdd(&pos[(v >> 15) & 63], 1u);
        csr_src[(size_t)g * E_EDGES + r] = (int)(v & 0x7fffu);
    }
}

// ---------- MFMA GEMM body (fp16) + fused as/ad epilogue ----------
template<int KDIM, int NCOL, bool CVT>
__device__ __forceinline__ void mm_body(int bid, char* smemc,
                                        const void* __restrict__ pXv, const void* __restrict__ sXv,
                                        const short* __restrict__ wt,
                                        const float* __restrict__ pa, const float* __restrict__ sa,
                                        uint16_t* __restrict__ outb,
                                        float* __restrict__ as_, float* __restrict__ ad_) {
    constexpr int NT = NCOL / 16;
    int g = bid / MM_BPG;
    int brow = (bid % MM_BPG) * 128;
    const short* wtg = wt + (g ? (size_t)NCOL * KDIM : 0);
    short* As = (short*)smemc;          // 128*40
    short* Bh = As + 128 * 40;          // NCOL*40
    short* Bl = Bh + NCOL * 40;         // NCOL*40
    int tid = threadIdx.x;
    int w = tid >> 6, l = tid & 63;
    int lr = l & 15, kq = l >> 4;
    f32x4 acc[2][NT] = {};
    for (int k0 = 0; k0 < KDIM; k0 += 32) {
        if (CVT) {
            const float* X = (g == 0) ? (const float*)pXv
                                      : (const float*)sXv + (size_t)(g - 1) * N_NODES * KDIM;
#pragma unroll
            for (int i = 0; i < 4; ++i) {                 // 128 rows x 8 float4 = 1024 transactions
                int v = tid + i * 256;
                int r = v >> 3, q = v & 7;
                float4 xv = make_float4(0.f, 0.f, 0.f, 0.f);
                if (brow + r < N_NODES)
                    xv = *(const float4*)(X + (size_t)(brow + r) * KDIM + k0 + q * 4);
                uint2 pkd; pkd.x = pkh2(xv.x, xv.y); pkd.y = pkh2(xv.z, xv.w);
                *(uint2*)(As + r * 40 + q * 4) = pkd;
            }
        } else {
            const uint16_t* X = (g == 0) ? (const uint16_t*)pXv
                                         : (const uint16_t*)sXv + (size_t)(g - 1) * N_NODES * KDIM;
#pragma unroll
            for (int i = 0; i < 2; ++i) {                 // 128 rows x 4 uint4 = 512 transactions
                int v = tid + i * 256;
                int r = v >> 2, q = v & 3;
                uint4 xv = make_uint4(0u, 0u, 0u, 0u);
                if (brow + r < N_NODES)
                    xv = *(const uint4*)(X + (size_t)(brow + r) * KDIM + k0 + q * 8);
                *(uint4*)(As + r * 40 + q * 8) = xv;
            }
        }
        for (int v = tid; v < NCOL * 4; v += 256) {       // B: NCOL rows x 4 uint4, hi+lo
            int r = v >> 2, q = v & 3;
            const short* srcp = wtg + (size_t)r * KDIM + k0 + q * 8;
            *(uint4*)(Bh + r * 40 + q * 8) = *(const uint4*)srcp;
            *(uint4*)(Bl + r * 40 + q * 8) = *(const uint4*)(srcp + (size_t)2 * NCOL * KDIM);
        }
        __syncthreads();
        half8 a0 = *(const half8*)(As + (w * 32 + lr) * 40 + kq * 8);
        half8 a1 = *(const half8*)(As + (w * 32 + 16 + lr) * 40 + kq * 8);
#pragma unroll
        for (int ct = 0; ct < NT; ++ct) {
            half8 bh = *(const half8*)(Bh + (ct * 16 + lr) * 40 + kq * 8);
            half8 bl = *(const half8*)(Bl + (ct * 16 + lr) * 40 + kq * 8);
            acc[0][ct] = __builtin_amdgcn_mfma_f32_16x16x32_f16(a0, bh, acc[0][ct], 0, 0, 0);
            acc[0][ct] = __builtin_amdgcn_mfma_f32_16x16x32_f16(a0, bl, acc[0][ct], 0, 0, 0);
            acc[1][ct] = __builtin_amdgcn_mfma_f32_16x16x32_f16(a1, bh, acc[1][ct], 0, 0, 0);
            acc[1][ct] = __builtin_amdgcn_mfma_f32_16x16x32_f16(a1, bl, acc[1][ct], 0, 0, 0);
        }
        __syncthreads();
    }
    // epilogue: store f16 h; fused as/ad from fp32 acc
    const float* av = (g == 0) ? pa : sa;   // 2*NCOL floats: [a_src | a_dst]
    float aS[NT], aD[NT];
#pragma unroll
    for (int ct = 0; ct < NT; ++ct) {
        aS[ct] = av[ct * 16 + lr];
        aD[ct] = av[NCOL + ct * 16 + lr];
    }
#pragma unroll
    for (int rt = 0; rt < 2; ++rt) {
#pragma unroll
        for (int i = 0; i < 4; ++i) {
            int node = brow + w * 32 + rt * 16 + kq * 4 + i;
            float s = 0.f, d = 0.f;
#pragma unroll
            for (int ct = 0; ct < NT; ++ct) {
                float h = acc[rt][ct][i];
                s += h * aS[ct];
                d += h * aD[ct];
                if (node < N_NODES)
                    outb[((size_t)g * N_NODES + node) * NCOL + ct * 16 + lr] = f2h(h);
            }
#pragma unroll
            for (int off = 1; off < 16; off <<= 1) { s += __shfl_xor(s, off); d += __shfl_xor(d, off); }
            if (lr == 0 && node < N_NODES) {
                as_[(size_t)g * N_NODES + node] = s;
                ad_[(size_t)g * N_NODES + node] = d;
            }
        }
    }
}

// ================= kernels =================

// K0: csr_count ∥ wprep ∥ zero emb
__global__ __launch_bounds__(256) void k0_kernel(const int* __restrict__ pei, const int* __restrict__ sei,
                                                 unsigned* __restrict__ C,
                                                 const float* __restrict__ pW1, const float* __restrict__ sW1,
                                                 const float* __restrict__ pW2, const float* __restrict__ sW2,
                                                 short* __restrict__ w1t, short* __restrict__ w2t,
                                                 float* __restrict__ emb) {
    __shared__ unsigned cnt[NBUCK];
    int bid = blockIdx.x;
    if (bid < CNT_BLOCKS) {
        count_body(bid, cnt, pei, sei, C);
    } else if (bid < CNT_BLOCKS + WPREP_BLOCKS) {
        wprep_body(bid - CNT_BLOCKS, pW1, sW1, pW2, sW2, w1t, w2t);
    } else {
        int idx = (bid - CNT_BLOCKS - WPREP_BLOCKS) * 256 + threadIdx.x;
        if (idx < G_TOT * 64) emb[idx] = 0.f;
    }
}

// CSR phase B (unchanged, 512 threads)
__global__ __launch_bounds__(512) void csr_scan(unsigned* __restrict__ C, unsigned* __restrict__ BB) {
    int g = blockIdx.x;
    __shared__ unsigned tot[NBUCK + 1];
    unsigned* Cg = C + (size_t)g * NB * NBUCK;
    for (int b = threadIdx.x; b < NBUCK; b += 512) {
        unsigned s = 0;
        for (int k = 0; k < NB; ++k) s += Cg[(size_t)k * NBUCK + b];
        tot[b] = s;
    }
    __syncthreads();
    if (threadIdx.x == 0) {
        unsigned run = 0;
        for (int b = 0; b < NBUCK; ++b) { unsigned t = tot[b]; tot[b] = run; run += t; }
        tot[NBUCK] = run;
    }
    __syncthreads();
    for (int b = threadIdx.x; b <= NBUCK; b += 512) BB[(size_t)g * (NBUCK + 1) + b] = tot[b];
    for (int b = threadIdx.x; b < NBUCK; b += 512) {
        unsigned run = tot[b];
        for (int k = 0; k < NB; ++k) {
            unsigned t = Cg[(size_t)k * NBUCK + b];
            Cg[(size_t)k * NBUCK + b] = run;
            run += t;
        }
    }
}

// K2: mm1 first half ∥ csr_bucket
__global__ __launch_bounds__(256) void mm_bucket_kernel(const void* __restrict__ pXv, const void* __restrict__ sXv,
                                                        const short* __restrict__ wt,
                                                        const float* __restrict__ pa, const float* __restrict__ sa,
                                                        uint16_t* __restrict__ outb,
                                                        float* __restrict__ as_, float* __restrict__ ad_,
                                                        const int* __restrict__ pei, const int* __restrict__ sei,
                                                        const unsigned* __restrict__ C, unsigned* __restrict__ tmp) {
    constexpr int SM = (128 * 40 + HID * 40 * 2) * 2;   // 30720 B
    __shared__ __align__(16) char smem[SM];
    int bid = blockIdx.x;
    if (bid < MM_HALF_A)
        mm_body<IN_DIM, HID, true>(bid, smem, pXv, sXv, wt, pa, sa, outb, as_, ad_);
    else
        bucket_body(bid - MM_HALF_A, (unsigned*)smem, pei, sei, C, tmp);
}

// K3: mm1 second half ∥ csr_fine
__global__ __launch_bounds__(256) void mm_fine_kernel(const void* __restrict__ pXv, const void* __restrict__ sXv,
                                                      const short* __restrict__ wt,
                                                      const float* __restrict__ pa, const float* __restrict__ sa,
                                                      uint16_t* __restrict__ outb,
                                                      float* __restrict__ as_, float* __restrict__ ad_,
                                                      const unsigned* __restrict__ tmp, const unsigned* __restrict__ BB,
                                                      int* __restrict__ row, int* __restrict__ csr_src) {
    constexpr int SM = (128 * 40 + HID * 40 * 2) * 2;
    __shared__ __align__(16) char smem[SM];
    int bid = blockIdx.x;
    if (bid < MM_HALF_B)
        mm_body<IN_DIM, HID, true>(bid + MM_HALF_A, smem, pXv, sXv, wt, pa, sa, outb, as_, ad_);
    else {
        unsigned* cnt = (unsigned*)smem;
        fine_body(bid - MM_HALF_B, cnt, cnt + 64, tmp, BB, row, csr_src);
    }
}

// mm2 standalone
__global__ __launch_bounds__(256) void mm_only_kernel(const void* __restrict__ pXv, const void* __restrict__ sXv,
                                                      const short* __restrict__ wt,
                                                      const float* __restrict__ pa, const float* __restrict__ sa,
                                                      uint16_t* __restrict__ outb,
                                                      float* __restrict__ as_, float* __restrict__ ad_) {
    constexpr int SM = (128 * 40 + F_OUT * 40 * 2) * 2;  // 20480 B
    __shared__ __align__(16) char smem[SM];
    mm_body<HID, F_OUT, false>(blockIdx.x, smem, pXv, sXv, wt, pa, sa, outb, as_, ad_);
}

// ---------- GAT aggregation, F=128: online softmax + 2-deep pipelined f16 gather; pk_fma acc; f16 out ----------
__global__ __launch_bounds__(256) void agg128_kernel(const uint32_t* __restrict__ hb,
                                                     const float* __restrict__ as_, const float* __restrict__ ad_,
                                                     const int* __restrict__ row, const int* __restrict__ csr_src,
                                                     const float* __restrict__ pb, const float* __restrict__ sb,
                                                     uint32_t* __restrict__ h1p) {
    int node = blockIdx.x * 4 + (threadIdx.x >> 6);
    int g = node / N_NODES;
    int n = node - g * N_NODES;
    int lane = threadIdx.x & 63;
    int start = row[(size_t)g * (N_NODES + 1) + n];
    int end   = row[(size_t)g * (N_NODES + 1) + n + 1];
    const int* src = csr_src + (size_t)g * E_EDGES;
    const float* asg = as_ + (size_t)g * N_NODES;
    const uint32_t* hg = hb + (size_t)g * N_NODES * 64;
    const char* hgb = (const char*)hg;   // block-uniform base; 32-bit voffsets
    float ad_d = ad_[node];
    float e_self = leaky(asg[n] + ad_d);
    int grp = lane >> 4;                 // edge slot within quad
    int f = lane & 15;                   // uint4 slice: feats f*8 .. f*8+7
    int fb = f << 4;                     // byte offset within 256 B row
    float m = e_self, denomp = 0.f;
    h2 A0 = {}, A1 = {}, A2 = {}, A3 = {};   // 8 feats as 4 packed pairs
    for (int j0 = start; j0 < end; j0 += 64) {
        int j = j0 + lane;
        float e = -3.0e38f; int ofs0 = 0;
        if (j < end) { int s0 = src[j]; ofs0 = s0 << 8; e = leaky(asg[s0] + ad_d); }
        float cmax = e;
#pragma unroll
        for (int off = 32; off; off >>= 1) cmax = fmaxf(cmax, __shfl_xor(cmax, off));
        if (cmax > m) {                  // wave-uniform rescale (rare)
            float sc = __expf(m - cmax);
            denomp *= sc;
            _Float16 sh = (_Float16)sc;
            h2 s2 = {sh, sh};
            A0 *= s2; A1 *= s2; A2 *= s2; A3 *= s2;
            m = cmax;
        }
        float w0 = (j < end) ? __expf(e - m) : 0.f;
        denomp += w0;
        int cnt = min(64, end - j0);
        for (int t = 0; t < cnt; t += 8) {
            float w_[2]; int o_[2];
#pragma unroll
            for (int u = 0; u < 2; ++u) {
                int tt = t + u * 4 + grp;           // <= 63 always
                w_[u] = __shfl(w0, tt);
                o_[u] = __shfl(ofs0, tt);
            }
            uint4 hv_[2];
#pragma unroll
            for (int u = 0; u < 2; ++u)
                hv_[u] = *(const uint4*)(hgb + (unsigned)(o_[u] + fb));
#pragma unroll
            for (int u = 0; u < 2; ++u) {
                _Float16 wh = (_Float16)w_[u];
                h2 w2 = {wh, wh};
                uint4 hv = hv_[u];
                A0 += w2 * __builtin_bit_cast(h2, hv.x);
                A1 += w2 * __builtin_bit_cast(h2, hv.y);
                A2 += w2 * __builtin_bit_cast(h2, hv.z);
                A3 += w2 * __builtin_bit_cast(h2, hv.w);
            }
        }
    }
#pragma unroll
    for (int off = 32; off; off >>= 1) denomp += __shfl_xor(denomp, off);
#pragma unroll
    for (int off = 16; off <= 32; off <<= 1) {
        A0 += h2shflx(A0, off); A1 += h2shflx(A1, off);
        A2 += h2shflx(A2, off); A3 += h2shflx(A3, off);
    }
    if (lane < 16) {
        float wself = __expf(e_self - m);
        float inv = 1.f / (denomp + wself + 1e-16f);
        uint4 hv = *(const uint4*)(hg + (size_t)n * 64 + lane * 4);
        const float* b = (g == 0) ? pb : sb;
        float4 b0 = *(const float4*)(b + lane * 8);
        float4 b1 = *(const float4*)(b + lane * 8 + 4);
        float o0 = fmaxf(fmaf(wself, hlo(hv.x), (float)A0.x) * inv + b0.x, 0.f);
        float o1 = fmaxf(fmaf(wself, hhi(hv.x), (float)A0.y) * inv + b0.y, 0.f);
        float o2 = fmaxf(fmaf(wself, hlo(hv.y), (float)A1.x) * inv + b0.z, 0.f);
        float o3 = fmaxf(fmaf(wself, hhi(hv.y), (float)A1.y) * inv + b0.w, 0.f);
        float o4 = fmaxf(fmaf(wself, hlo(hv.z), (float)A2.x) * inv + b1.x, 0.f);
        float o5 = fmaxf(fmaf(wself, hhi(hv.z), (float)A2.y) * inv + b1.y, 0.f);
        float o6 = fmaxf(fmaf(wself, hlo(hv.w), (float)A3.x) * inv + b1.z, 0.f);
        float o7 = fmaxf(fmaf(wself, hhi(hv.w), (float)A3.y) * inv + b1.w, 0.f);
        uint4 o; o.x = pkh2(o0, o1); o.y = pkh2(o2, o3); o.z = pkh2(o4, o5); o.w = pkh2(o6, o7);
        *(uint4*)(h1p + (size_t)node * 64 + lane * 4) = o;
    }
}

// ---------- GAT aggregation, F=64: online softmax + 4-deep pipelined f16 gather; pk_fma acc; f16 out ----------
__global__ __launch_bounds__(256) void agg64_kernel(const uint32_t* __restrict__ hb,
                                                    const float* __restrict__ as_, const float* __restrict__ ad_,
                                                    const int* __restrict__ row, const int* __restrict__ csr_src,
                                                    const float* __restrict__ pb, const float* __restrict__ sb,
                                                    uint32_t* __restrict__ out2b) {
    int node = blockIdx.x * 4 + (threadIdx.x >> 6);
    int g = node / N_NODES;
    int n = node - g * N_NODES;
    int lane = threadIdx.x & 63;
    int start = row[(size_t)g * (N_NODES + 1) + n];
    int end   = row[(size_t)g * (N_NODES + 1) + n + 1];
    const int* src = csr_src + (size_t)g * E_EDGES;
    const float* asg = as_ + (size_t)g * N_NODES;
    const uint32_t* hg = hb + (size_t)g * N_NODES * 32;
    const char* hgb = (const char*)hg;   // 128 B rows
    float ad_d = ad_[node];
    float e_self = leaky(asg[n] + ad_d);
    int grp = lane >> 4;
    int f = lane & 15;                   // uint2 slice: feats f*4 .. f*4+3
    int fb = f << 3;
    float m = e_self, denomp = 0.f;
    h2 A0 = {}, A1 = {};
    for (int j0 = start; j0 < end; j0 += 64) {
        int j = j0 + lane;
        float e = -3.0e38f; int ofs0 = 0;
        if (j < end) { int s0 = src[j]; ofs0 = s0 << 7; e = leaky(asg[s0] + ad_d); }
        float cmax = e;
#pragma unroll
        for (int off = 32; off; off >>= 1) cmax = fmaxf(cmax, __shfl_xor(cmax, off));
        if (cmax > m) {
            float sc = __expf(m - cmax);
            denomp *= sc;
            _Float16 sh = (_Float16)sc;
            h2 s2 = {sh, sh};
            A0 *= s2; A1 *= s2;
            m = cmax;
        }
        float w0 = (j < end) ? __expf(e - m) : 0.f;
        denomp += w0;
        int cnt = min(64, end - j0);
        for (int t = 0; t < cnt; t += 16) {
            float w_[4]; int o_[4];
#pragma unroll
            for (int u = 0; u < 4; ++u) {
                int tt = t + u * 4 + grp;
                w_[u] = __shfl(w0, tt);
                o_[u] = __shfl(ofs0, tt);
            }
            uint2 hv_[4];
#pragma unroll
            for (int u = 0; u < 4; ++u)
                hv_[u] = *(const uint2*)(hgb + (unsigned)(o_[u] + fb));
#pragma unroll
            for (int u = 0; u < 4; ++u) {
                _Float16 wh = (_Float16)w_[u];
                h2 w2 = {wh, wh};
                uint2 hv = hv_[u];
                A0 += w2 * __builtin_bit_cast(h2, hv.x);
                A1 += w2 * __builtin_bit_cast(h2, hv.y);
            }
        }
    }
#pragma unroll
    for (int off = 32; off; off >>= 1) denomp += __shfl_xor(denomp, off);
#pragma unroll
    for (int off = 16; off <= 32; off <<= 1) {
        A0 += h2shflx(A0, off); A1 += h2shflx(A1, off);
    }
    if (lane < 16) {
        float wself = __expf(e_self - m);
        float inv = 1.f / (denomp + wself + 1e-16f);
        uint2 hv = *(const uint2*)(hg + (size_t)n * 32 + lane * 2);
        const float* b = (g == 0) ? pb : sb;
        float4 bv = *(const float4*)(b + lane * 4);
        float o0 = fmaf(wself, hlo(hv.x), (float)A0.x) * inv + bv.x;
        float o1 = fmaf(wself, hhi(hv.x), (float)A0.y) * inv + bv.y;
        float o2 = fmaf(wself, hlo(hv.y), (float)A1.x) * inv + bv.z;
        float o3 = fmaf(wself, hhi(hv.y), (float)A1.y) * inv + bv.w;
        uint2 o; o.x = pkh2(o0, o1); o.y = pkh2(o2, o3);
        *(uint2*)(out2b + (size_t)node * 32 + lane * 2) = o;
    }
}

// ---------- mean over nodes (f16 in) -> emb[g][64] ----------
__global__ __launch_bounds__(256) void mean_kernel(const uint32_t* __restrict__ out2b, float* __restrict__ emb) {
    constexpr int CH = 32;
    int g = blockIdx.x / CH, chunk = blockIdx.x % CH;
    int sub = threadIdx.x >> 5;          // 8 node groups
    int q = threadIdx.x & 31;            // u32 idx: feats 2q, 2q+1
    const uint32_t* og = out2b + (size_t)g * N_NODES * 32;
    float a0 = 0.f, a1 = 0.f;
    for (int n = chunk * 8 + sub; n < N_NODES; n += CH * 8) {
        uint32_t v = og[(size_t)n * 32 + q];
        a0 += hlo(v); a1 += hhi(v);
    }
    __shared__ float red[256][2];
    red[threadIdx.x][0] = a0; red[threadIdx.x][1] = a1;
    __syncthreads();
    if (sub == 0) {
        float s0 = 0.f, s1 = 0.f;
        for (int k = 0; k < 8; ++k) { s0 += red[k * 32 + q][0]; s1 += red[k * 32 + q][1]; }
        atomicAdd(&emb[g * 64 + 2 * q],     s0 * (1.f / N_NODES));
        atomicAdd(&emb[g * 64 + 2 * q + 1], s1 * (1.f / N_NODES));
    }
}

// ---------- cosine-similarity head ----------
__global__ __launch_bounds__(64) void final_kernel(const float* __restrict__ emb,
                                                   const float* __restrict__ temp, float* __restrict__ out) {
    int lane = threadIdx.x;
    float pe = emb[lane];
    float pp = pe * pe;
#pragma unroll
    for (int off = 32; off; off >>= 1) pp += __shfl_xor(pp, off);
    float t = temp[0];
    float pn = sqrtf(pp);
    for (int s_i = 0; s_i < S_STORIES; ++s_i) {
        float se = emb[(1 + s_i) * 64 + lane];
        float ss = se * se;
        float dt = se * pe;
#pragma unroll
        for (int off = 32; off; off >>= 1) { ss += __shfl_xor(ss, off); dt += __shfl_xor(dt, off); }
        if (lane == 0) out[s_i] = dt / (sqrtf(ss) * pn * t);
    }
}

extern "C" void kernel_launch(void* const* d_in, const int* in_sizes, int n_in,
                              void* d_out, int out_size, void* d_ws, size_t ws_size,
                              hipStream_t stream) {
    const float* persona_x = (const float*)d_in[0];
    const int*   pei       = (const int*)d_in[1];
    const float* story_x   = (const float*)d_in[2];
    const int*   sei       = (const int*)d_in[3];
    const float* p_W1 = (const float*)d_in[4];
    const float* p_a1 = (const float*)d_in[5];
    const float* p_b1 = (const float*)d_in[6];
    const float* p_W2 = (const float*)d_in[7];
    const float* p_a2 = (const float*)d_in[8];
    const float* p_b2 = (const float*)d_in[9];
    const float* s_W1 = (const float*)d_in[10];
    const float* s_a1 = (const float*)d_in[11];
    const float* s_b1 = (const float*)d_in[12];
    const float* s_W2 = (const float*)d_in[13];
    const float* s_a2 = (const float*)d_in[14];
    const float* s_b2 = (const float*)d_in[15];
    const float* temp = (const float*)d_in[16];
    float* out = (float*)d_out;

    char* ws = (char*)d_ws;
    size_t off = 0;
    auto alloc = [&](size_t bytes) { char* p = ws + off; off += (bytes + 255) & ~(size_t)255; return p; };
    uint32_t* hb1  = (uint32_t*)alloc((size_t)G_TOT * N_NODES * 64 * 4);   // f16 h1; out2b alias
    uint32_t* h1p  = (uint32_t*)alloc((size_t)G_TOT * N_NODES * 64 * 4);   // f16 h1'; CSR C/BB alias
    uint32_t* hb2  = (uint32_t*)alloc((size_t)G_TOT * N_NODES * 32 * 4);   // f16 h2; CSR tmp alias (84.48 MB both)
    float* as_     = (float*)alloc((size_t)G_TOT * N_NODES * 4);
    float* ad_     = (float*)alloc((size_t)G_TOT * N_NODES * 4);
    int*   csr_row = (int*)  alloc((size_t)G_TOT * (N_NODES + 1) * 4);
    int*   csr_src = (int*)  alloc((size_t)G_TOT * E_EDGES * 4);
    float* emb     = (float*)alloc((size_t)G_TOT * 64 * 4);
    short* w1t     = (short*)alloc((size_t)2 * 2 * HID * IN_DIM * 2);      // [plane][type][col][K]
    short* w2t     = (short*)alloc((size_t)2 * 2 * F_OUT * HID * 2);
    if (off > ws_size) {
        fprintf(stderr, "kernel_launch: ws too small: need %zu have %zu\n", off, ws_size);
        return;
    }
    // CSR scratch aliases: tmp -> hb2 (dead until mm2); C/BB -> h1p (dead until agg128).
    unsigned* tmp = (unsigned*)hb2;
    unsigned* C   = (unsigned*)h1p;
    unsigned* BB  = (unsigned*)h1p + (size_t)G_TOT * NB * NBUCK;
    uint32_t* out2b = hb1;                                             // hb1 dead after agg128

    const int NODE_BLOCKS = G_TOT * N_NODES / 4; // 165000, exact

    // K0: csr_count ∥ wprep ∥ zero(emb)
    k0_kernel<<<CNT_BLOCKS + WPREP_BLOCKS + ZERO_BLOCKS, 256, 0, stream>>>(
        pei, sei, C, p_W1, s_W1, p_W2, s_W2, w1t, w2t, emb);
    // K1: per-graph scan
    csr_scan<<<G_TOT, 512, 0, stream>>>(C, BB);
    // K2: mm1 (first half) ∥ csr_bucket
    mm_bucket_kernel<<<MM_HALF_A + CNT_BLOCKS, 256, 0, stream>>>(
        persona_x, story_x, w1t, p_a1, s_a1, (uint16_t*)hb1, as_, ad_, pei, sei, C, tmp);
    // K3: mm1 (second half) ∥ csr_fine
    mm_fine_kernel<<<MM_HALF_B + FINE_BLOCKS, 256, 0, stream>>>(
        persona_x, story_x, w1t, p_a1, s_a1, (uint16_t*)hb1, as_, ad_, tmp, BB, csr_row, csr_src);

    // Layer 1 aggregation
    agg128_kernel<<<NODE_BLOCKS, 256, 0, stream>>>(hb1, as_, ad_, csr_row, csr_src, p_b1, s_b1, h1p);

    // Layer 2 (A operand already f16; as/ad fused) — hb2 (tmp) now dead, safe to overwrite
    const uint16_t* h1p16 = (const uint16_t*)h1p;
    mm_only_kernel<<<MM_BLOCKS, 256, 0, stream>>>(h1p16, h1p16 + (size_t)N_NODES * HID, w2t, p_a2, s_a2,
                                                  (uint16_t*)hb2, as_, ad_);
    agg64_kernel<<<NODE_BLOCKS, 256, 0, stream>>>(hb2, as_, ad_, csr_row, csr_src, p_b2, s_b2, out2b);

    // Readout
    mean_kernel<<<G_TOT * 32, 256, 0, stream>>>(out2b, emb);
    final_kernel<<<1, 64, 0, stream>>>(emb, temp, out);
}